// Round 2
// baseline (475.500 us; speedup 1.0000x reference)
//
#include <hip/hip_runtime.h>
#include <hip/hip_bf16.h>
#include <math.h>

#define NUM_TREES 20000
#define MAX_DEPTH 8
#define MAX_SIZE  40
#define VOCAB     30000
#define DIM       128
#define TOT       (MAX_DEPTH * MAX_SIZE)   // 320 tokens per tree

__device__ __forceinline__ double waveSumD(double v) {
    v += __shfl_xor(v, 32);
    v += __shfl_xor(v, 16);
    v += __shfl_xor(v, 8);
    v += __shfl_xor(v, 4);
    v += __shfl_xor(v, 2);
    v += __shfl_xor(v, 1);
    return v;
}
__device__ __forceinline__ double waveMaxD(double v) {
    v = fmax(v, __shfl_xor(v, 32));
    v = fmax(v, __shfl_xor(v, 16));
    v = fmax(v, __shfl_xor(v, 8));
    v = fmax(v, __shfl_xor(v, 4));
    v = fmax(v, __shfl_xor(v, 2));
    v = fmax(v, __shfl_xor(v, 1));
    return v;
}

// masks may arrive as 1-byte bool or int32; probe word 0 (all-ones input:
// byte layout reads 0x01010101, int32 layout reads 0x00000001).
__device__ __forceinline__ int loadMask(const void* m, size_t idx, bool asByte) {
    return asByte ? (int)((const unsigned char*)m)[idx] : ((const int*)m)[idx];
}

// Phase 0: ts[v] = dot(embedding[v], context_weight) in fp64 (one wave per row)
__global__ __launch_bounds__(256) void tokscore_kernel(
        const float* __restrict__ emb, const float* __restrict__ cw,
        double* __restrict__ ts) {
    int row  = (blockIdx.x * blockDim.x + threadIdx.x) >> 6;
    int lane = threadIdx.x & 63;
    if (row >= VOCAB) return;
    float2 e2 = *(const float2*)(emb + (size_t)row * DIM + lane * 2);
    float2 w2 = *(const float2*)(cw + lane * 2);
    double p = (double)e2.x * (double)w2.x + (double)e2.y * (double)w2.y;
    p = waveSumD(p);
    if (lane == 0) ts[row] = p;
}

// Phase 1+2 fused: fp64 scalar recursion -> 320 coefficients -> weighted
// gather-sum of embedding rows (fp64 accumulate). One block per tree.
__global__ __launch_bounds__(256) void encode_kernel(
        const int* __restrict__ tokens, const void* __restrict__ masks,
        const float* __restrict__ emb, const double* __restrict__ ts,
        float* __restrict__ out) {
    __shared__ int           s_tok[TOT];
    __shared__ double        s_e[TOT];
    __shared__ unsigned char s_val[TOT];
    __shared__ unsigned char s_msk[TOT];
    __shared__ double        s_coef[TOT];
    __shared__ double        s_red[8][DIM];

    const int tree = blockIdx.x;
    const int tid  = threadIdx.x;
    const size_t base = (size_t)tree * TOT;
    const bool mByte = (((const int*)masks)[0] != 1);   // see loadMask comment

    for (int i = tid; i < TOT; i += 256) {
        int t = tokens[base + i];
        int m = loadMask(masks, base + i, mByte);
        int tc = t < 0 ? 0 : t;
        s_tok[i] = tc;
        s_e[i]   = ts[tc];
        s_msk[i] = (unsigned char)(m != 0);
        s_val[i] = (unsigned char)((m != 0) && t >= 0);
    }
    __syncthreads();

    // Scalar recursion on wave 0: lanes = sibling positions (s < 40 active)
    if (tid < 64) {
        const int s = tid;
        const bool inS = s < MAX_SIZE;

        double e7 = 0.0, v7 = 0.0;
        if (inS) {
            e7 = s_e[7 * MAX_SIZE + s];
            v7 = s_val[7 * MAX_SIZE + s] ? 1.0 : 0.0;
        }
        double pw = waveSumD(e7 * v7);

        double cArr[MAX_DEPTH - 1];
        #pragma unroll
        for (int d = MAX_DEPTH - 2; d >= 0; --d) {
            double e = 0.0, vd = 0.0, mnext = 0.0;
            if (inS) {
                e     = s_e[d * MAX_SIZE + s];
                vd    = s_val[d * MAX_SIZE + s] ? 1.0 : 0.0;
                mnext = s_msk[(d + 1) * MAX_SIZE + s] ? 1.0 : 0.0;
            }
            double ncf = fmax(waveSumD(mnext), 1.0);          // child count
            double child = (vd > 0.0 && (double)s < ncf) ? 1.0 : 0.0;
            double gate  = 1.0 / (1.0 + exp(-e));
            double a     = e + gate * child * pw;
            double am    = vd > 0.0 ? a : -__builtin_inf();
            double mx    = waveMaxD(am);
            double ex    = vd > 0.0 ? exp(a - mx) : 0.0;
            double den   = waveSumD(ex);
            double attn  = ex / den;
            double c     = waveSumD(attn * gate * child);
            pw = waveSumD(attn * e) + c * pw;
            if (inS) s_coef[d * MAX_SIZE + s] = attn;
            cArr[d] = c;
        }
        double prefix = 1.0;
        #pragma unroll
        for (int d = 0; d <= MAX_DEPTH - 2; ++d) {
            if (inS) s_coef[d * MAX_SIZE + s] *= prefix;
            prefix *= cArr[d];
        }
        if (inS) s_coef[7 * MAX_SIZE + s] = prefix * v7;
    }
    __syncthreads();

    // Weighted gather-sum: out[tree] = sum_i coef[i] * emb[tok[i]]
    // 8 groups of 32 lanes; 32 lanes x float4 = one contiguous 512B row read.
    const int grp = tid >> 5;
    const int col = (tid & 31) << 2;
    double ax = 0.0, ay = 0.0, az = 0.0, aw = 0.0;
    for (int i = grp; i < TOT; i += 8) {
        double wgt = s_coef[i];
        if (wgt != 0.0) {
            const float4 v = *(const float4*)(emb + (size_t)s_tok[i] * DIM + col);
            ax += wgt * (double)v.x;
            ay += wgt * (double)v.y;
            az += wgt * (double)v.z;
            aw += wgt * (double)v.w;
        }
    }
    s_red[grp][col + 0] = ax;
    s_red[grp][col + 1] = ay;
    s_red[grp][col + 2] = az;
    s_red[grp][col + 3] = aw;
    __syncthreads();
    if (tid < DIM) {
        double r = 0.0;
        #pragma unroll
        for (int g = 0; g < 8; ++g) r += s_red[g][tid];
        out[(size_t)tree * DIM + tid] = (float)r;
    }
}

extern "C" void kernel_launch(void* const* d_in, const int* in_sizes, int n_in,
                              void* d_out, int out_size, void* d_ws, size_t ws_size,
                              hipStream_t stream) {
    const int*   tokens = (const int*)d_in[0];
    const void*  masks  = d_in[1];
    const float* emb    = (const float*)d_in[2];
    const float* cw     = (const float*)d_in[3];
    float*       out    = (float*)d_out;
    double*      ts     = (double*)d_ws;   // 30000 doubles = 240 KB scratch

    int ts_blocks = (VOCAB * 64 + 255) / 256;   // one wave per vocab row
    tokscore_kernel<<<ts_blocks, 256, 0, stream>>>(emb, cw, ts);
    encode_kernel<<<NUM_TREES, 256, 0, stream>>>(tokens, masks, emb, ts, out);
}